// Round 7
// baseline (514.575 us; speedup 1.0000x reference)
//
#include <hip/hip_runtime.h>
#include <hip/hip_bf16.h>

#define M_TOK 2048
#define KDIM 2048
#define NDIM 1408
#define NEXP 8
#define RROWS (M_TOK * 2)
#define CAP 1024

typedef __attribute__((ext_vector_type(8))) short short8;
typedef __attribute__((ext_vector_type(4))) float f32x4;

__device__ __forceinline__ unsigned short bf16rn(float f) {
    unsigned int u = __builtin_bit_cast(unsigned int, f);
    u += 0x7FFFu + ((u >> 16) & 1u);
    return (unsigned short)(u >> 16);
}
__device__ __forceinline__ unsigned int pk2(float a, float b) {
    return (unsigned int)bf16rn(a) | ((unsigned int)bf16rn(b) << 16);
}
// packed fp32x2 -> bf16x2 (RNE), compiler emits v_cvt_pk_bf16_f32
__device__ __forceinline__ unsigned int cvtpk(float a, float b) {
    __hip_bfloat162 h = __float22bfloat162_rn(make_float2(a, b));
    unsigned int u;
    __builtin_memcpy(&u, &h, 4);
    return u;
}

// async global->LDS, 16 B per lane; LDS dest wave-uniform base + lane*16
__device__ __forceinline__ void glds16(const void* g, void* l) {
    __builtin_amdgcn_global_load_lds(
        (const __attribute__((address_space(1))) unsigned int*)g,
        (__attribute__((address_space(3))) unsigned int*)l, 16, 0, 0);
}

// ---------------- routing + dispatch (fp32 -> bf16 row copy) ----------------
__global__ void k_route(const float* __restrict__ h, const int* __restrict__ idx,
                        int* __restrict__ cnt, int* __restrict__ slot_of,
                        unsigned short* __restrict__ bufA) {
    int r = blockIdx.x;
    __shared__ int s_ep;
    if (threadIdx.x == 0) {
        int e = idx[r];
        int p = atomicAdd(&cnt[e], 1);
        int ep = e * CAP + p;
        slot_of[r] = ep;
        s_ep = ep;
    }
    __syncthreads();
    int ep = s_ep;
    const float4* src = (const float4*)(h + (size_t)(r >> 1) * KDIM) + threadIdx.x * 2;
    float4 a = src[0], b = src[1];
    uint4 o;
    o.x = pk2(a.x, a.y); o.y = pk2(a.z, a.w);
    o.z = pk2(b.x, b.y); o.w = pk2(b.z, b.w);
    *((uint4*)(bufA + (size_t)ep * KDIM) + threadIdx.x) = o;
}

// ---------------- weight reorder: [E][R][C] fp32 -> [E][C/64][R][64] bf16 ---
// Per instr: 64 lanes read 1 KB contiguous of one row; writes land as 128-B
// runs per 64-col chunk (16 lanes x 8 B ascending). HBM-friendly both sides.
__global__ __launch_bounds__(256)
void k_reorder(const float* __restrict__ in, unsigned short* __restrict__ out,
               int R, int C) {
    const int e = blockIdx.x;        // 8
    const int slab = blockIdx.y;     // R/64 row-slab
    const int span = blockIdx.z;     // 256-col span
    const int NC = C >> 6;
    const int tid = threadIdx.x;
    const int wave = tid >> 6, lane = tid & 63;
    const int c = span * 256 + lane * 4;
    if (c >= C) return;
    const int r0 = slab * 64 + wave * 16;
    const float* src = in + ((size_t)e * R + r0) * C + c;
    unsigned short* dst = out + (((size_t)e * NC + (c >> 6)) * R + r0) * 64 + (c & 63);
#pragma unroll
    for (int i = 0; i < 16; i++) {
        float4 v = *(const float4*)(src + (size_t)i * C);
        uint2 o;
        o.x = cvtpk(v.x, v.y);
        o.y = cvtpk(v.z, v.w);
        *(uint2*)(dst + i * 64) = o;
    }
}

// ---------------- GEMM1: g,u = A @ W^T ; h = silu(min(g,10)) * clip(u) ------
// 128x64 tile. All operands via glds16 from K-chunked bf16 layouts.
// Schedule per K-step: vmcnt(0) [own prev DMAs]; barrier; issue next DMAs; MFMA.
__global__ __launch_bounds__(256, 2)
void k_gemm1(const unsigned short* __restrict__ bufA,
             const unsigned short* __restrict__ gwb,
             const unsigned short* __restrict__ uwb,
             const int* __restrict__ cnt, unsigned short* __restrict__ hbuf) {
    const int f = blockIdx.x;
    const int e = f & 7;             // expert -> XCD
    const int t = f >> 3;
    const int n_blk = t % 22;
    const int m_blk = t / 22;        // 0..7
    const int m0 = m_blk * 128;
    if (m0 >= cnt[e]) return;
    const int n0 = n_blk * 64;

    const unsigned short* A = bufA + (size_t)e * CAP * KDIM;
    const unsigned short* Gc = gwb + (size_t)e * 32 * NDIM * 64;
    const unsigned short* Uc = uwb + (size_t)e * 32 * NDIM * 64;

    __shared__ unsigned short sA[2][128 * 64];  // 2x16 KB
    __shared__ unsigned short sG[2][64 * 64];   // 2x8 KB
    __shared__ unsigned short sU[2][64 * 64];   // 2x8 KB  -> 64 KB total

    const int tid = threadIdx.x;
    const int lane = tid & 63;
    const int wave = tid >> 6;
    const int wm = (wave >> 1) * 64, wn = (wave & 1) * 32;
    const int q = lane >> 4, l15 = lane & 15;
    // DMA source swizzle: lane covers (row_in_seg = lane>>3, granule (lane&7)^(row&7))
    const int sr = lane >> 3;
    const int scb = (lane & 7) ^ (sr & 7);
    const int xi = l15 & 7;                 // reader xor key
    const int cbl0 = (q ^ xi) * 8;
    const int cbl1 = ((4 + q) ^ xi) * 8;

    f32x4 accG[4][2] = {};
    f32x4 accU[4][2] = {};

#define STAGE1(kc, b) do {                                                              \
        _Pragma("unroll")                                                               \
        for (int c_ = 0; c_ < 4; c_++) {                                                \
            int seg = wave * 4 + c_;                                                    \
            glds16(A + (size_t)(m0 + seg * 8 + sr) * KDIM + (kc) * 64 + scb * 8,        \
                   &sA[b][seg * 512]);                                                  \
        }                                                                               \
        _Pragma("unroll")                                                               \
        for (int c_ = 0; c_ < 2; c_++) {                                                \
            int seg = wave * 2 + c_;                                                    \
            glds16(Gc + ((size_t)(kc) * NDIM + n0 + seg * 8 + sr) * 64 + scb * 8,       \
                   &sG[b][seg * 512]);                                                  \
            glds16(Uc + ((size_t)(kc) * NDIM + n0 + seg * 8 + sr) * 64 + scb * 8,       \
                   &sU[b][seg * 512]);                                                  \
        }                                                                               \
    } while (0)

    STAGE1(0, 0);

    for (int kc = 0; kc < 32; kc++) {
        const int cur = kc & 1;
        asm volatile("s_waitcnt vmcnt(0)" ::: "memory");  // own DMAs for kc done
        __builtin_amdgcn_sched_barrier(0);
        __builtin_amdgcn_s_barrier();                     // everyone's done; prev read-buf free
        __builtin_amdgcn_sched_barrier(0);
        if (kc + 1 < 32) STAGE1(kc + 1, cur ^ 1);         // flies across MFMA phase

#pragma unroll
        for (int kh = 0; kh < 2; kh++) {
            const int co = kh ? cbl1 : cbl0;
            short8 af[4], gf[2], uf[2];
#pragma unroll
            for (int i = 0; i < 4; i++)
                af[i] = *(const short8*)&sA[cur][(wm + i * 16 + l15) * 64 + co];
#pragma unroll
            for (int j = 0; j < 2; j++) {
                gf[j] = *(const short8*)&sG[cur][(wn + j * 16 + l15) * 64 + co];
                uf[j] = *(const short8*)&sU[cur][(wn + j * 16 + l15) * 64 + co];
            }
#pragma unroll
            for (int i = 0; i < 4; i++)
#pragma unroll
                for (int j = 0; j < 2; j++) {
                    accG[i][j] = __builtin_amdgcn_mfma_f32_16x16x32_bf16(af[i], gf[j], accG[i][j], 0, 0, 0);
                    accU[i][j] = __builtin_amdgcn_mfma_f32_16x16x32_bf16(af[i], uf[j], accU[i][j], 0, 0, 0);
                }
        }
    }
#undef STAGE1

    unsigned short* H = hbuf + (size_t)e * CAP * NDIM;
#pragma unroll
    for (int i = 0; i < 4; i++)
#pragma unroll
        for (int j = 0; j < 2; j++) {
            int col = n0 + wn + j * 16 + l15;
#pragma unroll
            for (int rg = 0; rg < 4; rg++) {
                int row = m0 + wm + i * 16 + q * 4 + rg;
                float g = accG[i][j][rg];
                float u = accU[i][j][rg];
                g = fminf(g, 10.f);
                u = fminf(fmaxf(u, -10.f), 10.f);
                float hv = g / (1.f + __expf(-g)) * u;
                H[(size_t)row * NDIM + col] = bf16rn(hv);
            }
        }
}

// ---------------- GEMM2: d = h @ dw^T -> dbuf (fp32, no atomics) ------------
// 128x64 tile, 3 blocks/CU, same 1-barrier 1-vmcnt schedule, chunked dw.
__global__ __launch_bounds__(256, 3)
void k_gemm2(const unsigned short* __restrict__ hbuf,
             const unsigned short* __restrict__ dwb, const int* __restrict__ cnt,
             float* __restrict__ dbuf) {
    const int f = blockIdx.x;
    const int e = f & 7;
    const int t = f >> 3;
    const int n_blk = t & 31;        // over KDIM
    const int m_blk = t >> 5;        // 0..7
    const int cnt_e = cnt[e];
    const int m0 = m_blk * 128;
    if (m0 >= cnt_e) return;
    const int n0 = n_blk * 64;

    const unsigned short* Ah = hbuf + (size_t)e * CAP * NDIM;
    const unsigned short* Dc = dwb + (size_t)e * 22 * KDIM * 64;

    __shared__ unsigned short sA[2][128 * 64];  // 2x16 KB
    __shared__ unsigned short sB[2][64 * 64];   // 2x8 KB -> 48 KB

    const int tid = threadIdx.x;
    const int lane = tid & 63;
    const int wave = tid >> 6;
    const int wm = (wave >> 1) * 64, wn = (wave & 1) * 32;
    const int q = lane >> 4, l15 = lane & 15;
    const int sr = lane >> 3;
    const int scb = (lane & 7) ^ (sr & 7);
    const int xi = l15 & 7;
    const int cbl0 = (q ^ xi) * 8;
    const int cbl1 = ((4 + q) ^ xi) * 8;

    f32x4 acc[4][2] = {};

#define STAGE2(nc, b) do {                                                              \
        _Pragma("unroll")                                                               \
        for (int c_ = 0; c_ < 4; c_++) {                                                \
            int seg = wave * 4 + c_;                                                    \
            glds16(Ah + (size_t)(m0 + seg * 8 + sr) * NDIM + (nc) * 64 + scb * 8,       \
                   &sA[b][seg * 512]);                                                  \
        }                                                                               \
        _Pragma("unroll")                                                               \
        for (int c_ = 0; c_ < 2; c_++) {                                                \
            int seg = wave * 2 + c_;                                                    \
            glds16(Dc + ((size_t)(nc) * KDIM + n0 + seg * 8 + sr) * 64 + scb * 8,       \
                   &sB[b][seg * 512]);                                                  \
        }                                                                               \
    } while (0)

    STAGE2(0, 0);

    for (int nc = 0; nc < 22; nc++) {
        const int cur = nc & 1;
        asm volatile("s_waitcnt vmcnt(0)" ::: "memory");
        __builtin_amdgcn_sched_barrier(0);
        __builtin_amdgcn_s_barrier();
        __builtin_amdgcn_sched_barrier(0);
        if (nc + 1 < 22) STAGE2(nc + 1, cur ^ 1);

#pragma unroll
        for (int kh = 0; kh < 2; kh++) {
            const int co = kh ? cbl1 : cbl0;
            short8 af[4], bfr[2];
#pragma unroll
            for (int i = 0; i < 4; i++)
                af[i] = *(const short8*)&sA[cur][(wm + i * 16 + l15) * 64 + co];
#pragma unroll
            for (int j = 0; j < 2; j++)
                bfr[j] = *(const short8*)&sB[cur][(wn + j * 16 + l15) * 64 + co];
#pragma unroll
            for (int i = 0; i < 4; i++)
#pragma unroll
                for (int j = 0; j < 2; j++)
                    acc[i][j] = __builtin_amdgcn_mfma_f32_16x16x32_bf16(af[i], bfr[j], acc[i][j], 0, 0, 0);
        }
    }
#undef STAGE2

    float* D = dbuf + (size_t)e * CAP * KDIM;
#pragma unroll
    for (int i = 0; i < 4; i++) {
#pragma unroll
        for (int rg = 0; rg < 4; rg++) {
            int row = m0 + wm + i * 16 + q * 4 + rg;
            if (row < cnt_e) {
                float* drow = D + (size_t)row * KDIM + n0 + wn + l15;
#pragma unroll
                for (int j = 0; j < 2; j++)
                    drow[j * 16] = acc[i][j][rg];
            }
        }
    }
}

// ---------------- combine: out[tok] = g0*d[slot0] + g1*d[slot1] -------------
__global__ void k_combine(const float* __restrict__ dbuf, const int* __restrict__ slot_of,
                          const float* __restrict__ gate, float* __restrict__ out) {
    int tk = blockIdx.x;
    int s0 = slot_of[2 * tk], s1 = slot_of[2 * tk + 1];
    float g0 = gate[2 * tk], g1 = gate[2 * tk + 1];
    const float4* r0 = (const float4*)(dbuf + (size_t)s0 * KDIM);
    const float4* r1 = (const float4*)(dbuf + (size_t)s1 * KDIM);
    float4* o = (float4*)(out + (size_t)tk * KDIM);
    int i = threadIdx.x * 2;
#pragma unroll
    for (int c = 0; c < 2; c++) {
        float4 a = r0[i + c], b = r1[i + c];
        float4 v;
        v.x = g0 * a.x + g1 * b.x;
        v.y = g0 * a.y + g1 * b.y;
        v.z = g0 * a.z + g1 * b.z;
        v.w = g0 * a.w + g1 * b.w;
        o[i + c] = v;
    }
}

extern "C" void kernel_launch(void* const* d_in, const int* in_sizes, int n_in,
                              void* d_out, int out_size, void* d_ws, size_t ws_size,
                              hipStream_t stream) {
    const float* flat_h = (const float*)d_in[0];
    const int* flat_idx = (const int*)d_in[1];
    const float* flat_gate = (const float*)d_in[2];
    const float* gw = (const float*)d_in[3];
    const float* uw = (const float*)d_in[4];
    const float* dwn = (const float*)d_in[5];
    float* out = (float*)d_out;

    char* w = (char*)d_ws;
    int* cnt = (int*)w;                         // 256 B
    int* slot_of = (int*)(w + 256);             // 16 KB
    unsigned short* bufA = (unsigned short*)(w + 1048576ull);     // 32 MiB
    unsigned short* hbuf = (unsigned short*)(w + 34603008ull);    // 22 MiB
    unsigned short* gwb  = (unsigned short*)(w + 57671680ull);    // 46.1 MB (chunked bf16)
    unsigned short* uwb  = (unsigned short*)(w + 103809024ull);   // 46.1 MB
    unsigned short* dwb  = (unsigned short*)(w + 149946368ull);   // 46.1 MB -> ends ~187 MiB
    float* dbuf = (float*)(w + 57671680ull);    // aliases gwb/uwb (dead after gemm1), 64 MiB

    hipMemsetAsync(cnt, 0, 256, stream);

    k_route<<<RROWS, 256, 0, stream>>>(flat_h, flat_idx, cnt, slot_of, bufA);
    k_reorder<<<dim3(8, 22, 8), 256, 0, stream>>>(gw, gwb, NDIM, KDIM);
    k_reorder<<<dim3(8, 22, 8), 256, 0, stream>>>(uw, uwb, NDIM, KDIM);
    k_reorder<<<dim3(8, 32, 6), 256, 0, stream>>>(dwn, dwb, KDIM, NDIM);
    k_gemm1<<<8 * 22 * 8, 256, 0, stream>>>(bufA, gwb, uwb, cnt, hbuf);
    k_gemm2<<<8 * 32 * 8, 256, 0, stream>>>(hbuf, dwb, cnt, dbuf);
    k_combine<<<M_TOK, 256, 0, stream>>>(dbuf, slot_of, flat_gate, out);
}